// Round 1
// baseline (42.960 us; speedup 1.0000x reference)
//
#include <hip/hip_runtime.h>
#include <hip/hip_bf16.h>
#include <float.h>

// Problem constants (from reference setup_inputs)
#define B_  4
#define C_  256
#define H_  50
#define W_  50
#define R_  300
#define PH_ 7
#define PW_ 7

// One thread per output element (r, c, ph, pw), output layout [R, C, PH, PW]
// (pw fastest -> consecutive threads write contiguous floats).
// ROI params recomputed per thread (5 cached loads + few VALU ops, trivially cheap).
__global__ __launch_bounds__(256) void roi_pool_kernel(
    const float* __restrict__ fm,    // [B, C, H, W]
    const float* __restrict__ rois,  // [R, 5] = x0, y0, x1, y1, batch
    float* __restrict__ out)         // [R, C, PH, PW]
{
    const int total = R_ * C_ * PH_ * PW_;
    int t = blockIdx.x * blockDim.x + threadIdx.x;
    if (t >= total) return;

    int pw  = t % PW_;
    int tmp = t / PW_;
    int ph  = tmp % PH_;
    tmp /= PH_;
    int c = tmp % C_;
    int r = tmp / C_;

    // --- ROI decode (faithful to reference semantics, SPATIAL_SCALE == 1.0) ---
    const float* rp = rois + r * 5;
    float fx0 = rp[0], fy0 = rp[1], fx1 = rp[2], fy1 = rp[3], fb = rp[4];
    int b = (int)fb;  // trunc toward zero, matches astype(int32)

    // jnp.round == round-half-to-even == rintf (default rounding mode)
    int x0 = (int)rintf(fx0);
    int y0 = (int)rintf(fy0);
    int x1 = (int)rintf(fx1);
    int y1 = (int)rintf(fy1);
    x0 = min(max(x0, 0), W_ - 1);
    x1 = min(max(x1, 0), W_ - 1);
    y0 = min(max(y0, 0), H_ - 1);
    y1 = min(max(y1, 0), H_ - 1);
    x1 = max(x1, x0 + 1);
    y1 = max(y1, y0 + 1);
    int roi_w = x1 - x0;  // >= 1
    int roi_h = y1 - y0;  // >= 1

    // adaptive bin edges: start = floor(i*len/7), end = ceil((i+1)*len/7)
    int ws = x0 + (pw * roi_w) / PW_;
    int we = x0 + ((pw + 1) * roi_w + PW_ - 1) / PW_;
    int hs = y0 + (ph * roi_h) / PH_;
    int he = y0 + ((ph + 1) * roi_h + PH_ - 1) / PH_;
    // Note: he <= y1 <= H (so h <= H-1), we <= x1 <= W (so w <= W-1);
    // the reference's clip() is provably a no-op -> skip it.

    const float* p = fm + ((size_t)(b * C_ + c)) * (H_ * W_);

    float m = -FLT_MAX;
    for (int h = hs; h < he; ++h) {
        const float* row = p + h * W_;
        for (int w = ws; w < we; ++w) {
            m = fmaxf(m, row[w]);
        }
    }
    out[t] = m;
}

extern "C" void kernel_launch(void* const* d_in, const int* in_sizes, int n_in,
                              void* d_out, int out_size, void* d_ws, size_t ws_size,
                              hipStream_t stream)
{
    const float* fm   = (const float*)d_in[0];  // [4,256,50,50]
    const float* rois = (const float*)d_in[1];  // [300,5]
    float* out        = (float*)d_out;          // [300,256,7,7]

    const int total = R_ * C_ * PH_ * PW_;      // 3,763,200
    const int block = 256;
    const int grid  = (total + block - 1) / block;

    roi_pool_kernel<<<grid, block, 0, stream>>>(fm, rois, out);
}